// Round 10
// baseline (2546.778 us; speedup 1.0000x reference)
//
#include <hip/hip_runtime.h>

// B=128, T=48, I=128, H=512. Sequential 48-step attention+GRU scan.
// R10: THE RECURRENCE IS ROW-INDEPENDENT (h_new[b] depends only on h[b]).
// Zero cross-block sync: 64 blocks x 2 batch rows, fully block-local scan.
// GEMVs via v_dot2_f32_f16 with k-pair-major weights (coalesced loads, LDS
// same-addr h broadcast). Thread t owns z/gi cols {2t,2t+1}+512j, so gh and
// gi never leave registers. No atomics, no barriers, no fabric traffic.

typedef _Float16 half8 __attribute__((ext_vector_type(8)));
typedef _Float16 h2v  __attribute__((ext_vector_type(2)));

// ---------------- ws layout (bytes) ----------------
#define OFF_BZ   0u          // 2048 f32 : [b1 ; b_hh]
#define OFF_BC   8192u       // 1536 f32 : W_ih@b4 + b_ih
#define OFF_WZP  16384u      // 256*2048 u32 : Wz k-pair-major fp16x2
#define OFF_WCP  2113536u    // 66*1536 u32 : Wc k-pair-major fp16x2 (k=131 pad 0)
#define OFF_W2H  2519040u    // 128*48*512 f16 : dx@W2^T + b2

__device__ __forceinline__ float fexp2(float x) { return __builtin_amdgcn_exp2f(x); }
__device__ __forceinline__ float frcp(float x)  { return __builtin_amdgcn_rcpf(x); }
__device__ __forceinline__ float fast_tanh(float x) {
  x = fminf(fmaxf(x, -15.f), 15.f);
  float e = fexp2(x * 2.8853900817779268f);   // exp(2x)
  return (e - 1.f) * frcp(e + 1.f);
}
__device__ __forceinline__ float fast_sigmoid(float x) {
  x = fminf(fmaxf(x, -30.f), 30.f);
  float e = fexp2(x * 1.4426950408889634f);   // exp(x)
  return e * frcp(e + 1.f);
}

union UH2 { unsigned int u; h2v h; };

__device__ __forceinline__ unsigned int packh2(float a, float b) {
  UH2 t; t.h[0] = (_Float16)a; t.h[1] = (_Float16)b; return t.u;
}
__device__ __forceinline__ float fdot2u(unsigned int a, unsigned int b, float c) {
  UH2 ua, ub; ua.u = a; ub.u = b;
#if __has_builtin(__builtin_amdgcn_fdot2)
  return __builtin_amdgcn_fdot2(ua.h, ub.h, c, false);
#else
  return c + (float)ua.h[0] * (float)ub.h[0] + (float)ua.h[1] * (float)ub.h[1];
#endif
}

// ---------------- fused prep kernel (grid 273 x 256) ----------------
__global__ __launch_bounds__(256) void prep_all(
    const float* __restrict__ dx, const float* __restrict__ W1,
    const float* __restrict__ Whh, const float* __restrict__ b1,
    const float* __restrict__ bhh, const float* __restrict__ Wih,
    const float* __restrict__ W4, const float* __restrict__ b4,
    const float* __restrict__ bih, const float* __restrict__ W2,
    const float* __restrict__ b2,
    unsigned int* __restrict__ WzP, float* __restrict__ bz,
    float* __restrict__ bc, unsigned int* __restrict__ WcP,
    _Float16* __restrict__ w2h)
{
  __shared__ __align__(16) char smem[66816];
  const int bid = blockIdx.x;
  const int tid = threadIdx.x;
  const int lane = tid & 63, wv = tid >> 6;

  if (bid == 0) {                       // bz = [b1 ; bhh]
    for (int n = tid; n < 2048; n += 256)
      bz[n] = (n < 512) ? b1[n] : bhh[n - 512];
  } else if (bid < 17) {                // bc = Wih@b4 + bih : 16 x 96 rows
    const int o0 = (bid - 1) * 96 + wv * 24;
    for (int it = 0; it < 24; ++it) {
      const int row = o0 + it;
      const float* r = Wih + row * 512 + lane * 8;
      float s = 0.f;
#pragma unroll
      for (int u = 0; u < 8; ++u) s += r[u] * b4[lane * 8 + u];
#pragma unroll
      for (int off = 32; off >= 1; off >>= 1) s += __shfl_xor(s, off);
      if (lane == 0) bc[row] = bih[row] + s;
    }
  } else if (bid < 49) {                // WzP[k2][n] = (Wz[n][2k2], Wz[n][2k2+1])
    unsigned int* wt = (unsigned int*)smem;        // [64][261] (261: conflict-free)
    const int nbase = (bid - 17) * 64;
    for (int idx = tid; idx < 64 * 256; idx += 256) {
      int r = idx >> 8, k2 = idx & 255;
      int n = nbase + r;
      const float* src = (n < 512) ? (W1 + n * 512) : (Whh + (n - 512) * 512);
      float2 v = *(const float2*)(src + 2 * k2);
      wt[r * 261 + k2] = packh2(v.x, v.y);
    }
    __syncthreads();
    for (int idx = tid; idx < 256 * 64; idx += 256) {
      int k2 = idx >> 6, j = idx & 63;
      WzP[k2 * 2048 + nbase + j] = wt[j * 261 + k2];
    }
  } else if (bid < 145) {               // WcP: Wc = Wih@W4, k-pair-major (pad k=131)
    float* wih = (float*)smem;                 // 16*66
    float* w4s = (float*)(smem + 4224);        // 64*132
    const int o0 = (bid - 49) * 16;
    const int k = tid;
    float acc[16];
#pragma unroll
    for (int i = 0; i < 16; ++i) acc[i] = 0.f;
    for (int jc = 0; jc < 512; jc += 64) {
      __syncthreads();
      for (int idx = tid; idx < 16 * 64; idx += 256) {
        int oo = idx >> 6, jj = idx & 63;
        wih[oo * 66 + jj] = Wih[(o0 + oo) * 512 + jc + jj];
      }
      for (int idx = tid; idx < 64 * 131; idx += 256) {
        int r = idx / 131, c = idx - r * 131;
        w4s[r * 132 + c] = W4[(jc + r) * 131 + c];
      }
      __syncthreads();
      if (k < 131) {
        for (int jj = 0; jj < 64; ++jj) {
          float w4v = w4s[jj * 132 + k];
#pragma unroll
          for (int oo = 0; oo < 16; ++oo) acc[oo] += wih[oo * 66 + jj] * w4v;
        }
      }
    }
    if (k < 132) {                       // k==131 writes the zero pad
      unsigned short* wc16 = (unsigned short*)WcP;
#pragma unroll
      for (int oo = 0; oo < 16; ++oo) {
        _Float16 hv = (_Float16)((k < 131) ? acc[oo] : 0.f);
        wc16[((k >> 1) * 1536 + o0 + oo) * 2 + (k & 1)] = *(unsigned short*)&hv;
      }
    }
  } else {                              // w2h: 128 blocks, one batch row each
    float* dxa = (float*)smem;                 // 48*128 f32
    _Float16* w2t = (_Float16*)(smem + 24576); // 128*132 f16
    const int b = bid - 145;
    for (int idx = tid; idx < 48 * 128; idx += 256)
      dxa[idx] = dx[b * 6144 + idx];
    for (int hc = 0; hc < 4; ++hc) {
      __syncthreads();
      for (int idx = tid; idx < 128 * 128; idx += 256) {
        int hl = idx >> 7, i = idx & 127;
        w2t[i * 132 + hl] = (_Float16)W2[(hc * 128 + hl) * 128 + i];
      }
      __syncthreads();
      const int hh = tid & 127;
      const int tq = tid >> 7;
      const float b2v = b2[hc * 128 + hh];
      for (int tt = tq * 24; tt < tq * 24 + 24; ++tt) {
        float acc = b2v;
#pragma unroll 4
        for (int i = 0; i < 128; ++i)
          acc += dxa[tt * 128 + i] * (float)w2t[i * 132 + hh];
        w2h[(b * 48 + tt) * 512 + hc * 128 + hh] = (_Float16)acc;
      }
    }
  }
}

// ---------------- main: 64 blocks x 2 rows, zero cross-block sync ----------------
__global__ __launch_bounds__(256, 1) void decoder_main(
    const float* __restrict__ dx, const float* __restrict__ xin,
    const float* __restrict__ h0,
    const float* __restrict__ W3, const float* __restrict__ b3,
    const float* __restrict__ Wfc, const float* __restrict__ bfc,
    const unsigned int* __restrict__ WzP, const float* __restrict__ bz,
    const unsigned int* __restrict__ WcP, const float* __restrict__ bc,
    const _Float16* __restrict__ w2h, float* __restrict__ out)
{
  const int tid = threadIdx.x, lane = tid & 63, wv = tid >> 6;
  const int rA = blockIdx.x * 2, rB = rA + 1;
  const int t2 = tid * 2;

  __shared__ float dxs[2][48 * 128];     // 48 KB
  __shared__ unsigned int hp[2][256];    // h as fp16 pairs
  __shared__ float w1s[2][512];
  __shared__ float es[2][48];
  __shared__ float asx[2][48];
  __shared__ float ysf[2][132];
  __shared__ unsigned int ysp[2][66];
  __shared__ float wfcs[512];
  __shared__ float red[2][4];

  // ---- one-time staging ----
  for (int i = tid; i < 6144; i += 256) {
    dxs[0][i] = dx[rA * 6144 + i];
    dxs[1][i] = dx[rB * 6144 + i];
  }
  for (int i = tid; i < 512; i += 256) wfcs[i] = Wfc[i];
  float w3r[8];
#pragma unroll
  for (int u = 0; u < 8; ++u) w3r[u] = W3[lane * 8 + u];
  const float b3v = b3[0], bfcv = bfc[0];
  float bzr[8], bcr[6];
#pragma unroll
  for (int j = 0; j < 4; ++j) {
    bzr[2 * j] = bz[512 * j + t2]; bzr[2 * j + 1] = bz[512 * j + t2 + 1];
  }
#pragma unroll
  for (int j = 0; j < 3; ++j) {
    bcr[2 * j] = bc[512 * j + t2]; bcr[2 * j + 1] = bc[512 * j + t2 + 1];
  }
  float hA0 = h0[rA * 512 + t2], hA1 = h0[rA * 512 + t2 + 1];
  float hB0 = h0[rB * 512 + t2], hB1 = h0[rB * 512 + t2 + 1];
  hp[0][tid] = packh2(hA0, hA1);
  hp[1][tid] = packh2(hB0, hB1);
  __syncthreads();

  for (int step = 0; step < 48; ++step) {
    // ---- ph1: z[2048] = h . Wz^T + bz for both rows (dot2 GEMV) ----
    float accA[8], accB[8];
#pragma unroll
    for (int j = 0; j < 8; ++j) { accA[j] = bzr[j]; accB[j] = bzr[j]; }
#pragma unroll 2
    for (int k2 = 0; k2 < 256; ++k2) {
      const unsigned int ha = hp[0][k2], hb = hp[1][k2];   // LDS broadcast
      const unsigned int* wp = WzP + k2 * 2048 + t2;
#pragma unroll
      for (int j = 0; j < 4; ++j) {
        uint2 w = *(const uint2*)(wp + 512 * j);
        accA[2 * j]     = fdot2u(w.x, ha, accA[2 * j]);
        accA[2 * j + 1] = fdot2u(w.y, ha, accA[2 * j + 1]);
        accB[2 * j]     = fdot2u(w.x, hb, accB[2 * j]);
        accB[2 * j + 1] = fdot2u(w.y, hb, accB[2 * j + 1]);
      }
    }
    // w1 cols -> LDS; gh (accA[2..7]) stays in registers for the gates
    w1s[0][t2] = accA[0]; w1s[0][t2 + 1] = accA[1];
    w1s[1][t2] = accB[0]; w1s[1][t2 + 1] = accB[1];
    __syncthreads();

    // ---- ph2a: energies. wave -> (row = wv>>1, t-half = wv&1) ----
    {
      const int row = wv >> 1;
      const int r = (row == 0) ? rA : rB;
      float w1r[8];
#pragma unroll
      for (int u = 0; u < 8; ++u) w1r[u] = w1s[row][lane * 8 + u];
      const _Float16* __restrict__ w2row = w2h + (r * 48) * 512 + lane * 8;
      const int tb = (wv & 1) * 24;
      for (int tt = 0; tt < 24; ++tt) {
        const int t = tb + tt;
        half8 w2v = *(const half8*)(w2row + t * 512);
        float p = 0.f;
#pragma unroll
        for (int u = 0; u < 8; ++u)
          p += w3r[u] * fast_tanh(w1r[u] + (float)w2v[u]);
#pragma unroll
        for (int off = 32; off >= 1; off >>= 1) p += __shfl_xor(p, off);
        if (lane == 0) es[row][t] = p + b3v;
      }
    }
    __syncthreads();
    // ---- ph2b: softmax (wave0 -> row0, wave2 -> row1) ----
    if ((wv & 1) == 0) {
      const int row = wv >> 1;
      float e = (lane < 48) ? es[row][lane] : -1e30f;
      float mx = e;
#pragma unroll
      for (int off = 32; off >= 1; off >>= 1) mx = fmaxf(mx, __shfl_xor(mx, off));
      float pe = (lane < 48) ? fexp2((e - mx) * 1.4426950408889634f) : 0.f;
      float s = pe;
#pragma unroll
      for (int off = 32; off >= 1; off >>= 1) s += __shfl_xor(s, off);
      float a = pe * frcp(s);
      if (lane < 48) {
        asx[row][lane] = a;
        if (step == 47) out[128 + (rA + row) * 48 + lane] = a;   // alpha
      }
    }
    __syncthreads();
    // ---- ph2c: context + x_t + pad ----
    {
      const int row = tid >> 7, j = tid & 127;
      float acc = 0.f;
#pragma unroll 4
      for (int t = 0; t < 48; ++t) acc += asx[row][t] * dxs[row][t * 128 + j];
      ysf[row][j] = acc;
      if (j < 3) ysf[row][128 + j] = xin[((rA + row) * 48 + step) * 3 + j];
      if (j == 3) ysf[row][131] = 0.f;
    }
    __syncthreads();
    if (tid < 66)                       ysp[0][tid] = packh2(ysf[0][2 * tid], ysf[0][2 * tid + 1]);
    else if (tid >= 128 && tid < 194)   ysp[1][tid - 128] = packh2(ysf[1][2 * (tid - 128)], ysf[1][2 * (tid - 128) + 1]);
    __syncthreads();

    // ---- ph3: gi = y . Wc^T + bc (6 cols/thread/row) ; gates ; h_new ----
    float giA[6], giB[6];
#pragma unroll
    for (int j = 0; j < 6; ++j) { giA[j] = bcr[j]; giB[j] = bcr[j]; }
#pragma unroll 2
    for (int k2 = 0; k2 < 66; ++k2) {
      const unsigned int ya = ysp[0][k2], yb = ysp[1][k2];
      const unsigned int* wp = WcP + k2 * 1536 + t2;
#pragma unroll
      for (int j = 0; j < 3; ++j) {
        uint2 w = *(const uint2*)(wp + 512 * j);
        giA[2 * j]     = fdot2u(w.x, ya, giA[2 * j]);
        giA[2 * j + 1] = fdot2u(w.y, ya, giA[2 * j + 1]);
        giB[2 * j]     = fdot2u(w.x, yb, giB[2 * j]);
        giB[2 * j + 1] = fdot2u(w.y, yb, giB[2 * j + 1]);
      }
    }
    {
      float r0 = fast_sigmoid(giA[0] + accA[2]), r1 = fast_sigmoid(giA[1] + accA[3]);
      float z0 = fast_sigmoid(giA[2] + accA[4]), z1 = fast_sigmoid(giA[3] + accA[5]);
      float n0 = fast_tanh(giA[4] + r0 * accA[6]), n1 = fast_tanh(giA[5] + r1 * accA[7]);
      hA0 = (1.f - z0) * n0 + z0 * hA0;
      hA1 = (1.f - z1) * n1 + z1 * hA1;
      r0 = fast_sigmoid(giB[0] + accB[2]); r1 = fast_sigmoid(giB[1] + accB[3]);
      z0 = fast_sigmoid(giB[2] + accB[4]); z1 = fast_sigmoid(giB[3] + accB[5]);
      n0 = fast_tanh(giB[4] + r0 * accB[6]); n1 = fast_tanh(giB[5] + r1 * accB[7]);
      hB0 = (1.f - z0) * n0 + z0 * hB0;
      hB1 = (1.f - z1) * n1 + z1 * hB1;
      hp[0][tid] = packh2(hA0, hA1);
      hp[1][tid] = packh2(hB0, hB1);
    }
    __syncthreads();
  }

  // ---- epilogue: re = h_f . Wfc + bfc (both rows, register h) ----
  {
    float pA = hA0 * wfcs[t2] + hA1 * wfcs[t2 + 1];
    float pB = hB0 * wfcs[t2] + hB1 * wfcs[t2 + 1];
#pragma unroll
    for (int off = 32; off >= 1; off >>= 1) {
      pA += __shfl_xor(pA, off);
      pB += __shfl_xor(pB, off);
    }
    if (lane == 0) { red[0][wv] = pA; red[1][wv] = pB; }
    __syncthreads();
    if (tid == 0) out[rA] = red[0][0] + red[0][1] + red[0][2] + red[0][3] + bfcv;
    if (tid == 1) out[rB] = red[1][0] + red[1][1] + red[1][2] + red[1][3] + bfcv;
  }
}

extern "C" void kernel_launch(void* const* d_in, const int* in_sizes, int n_in,
                              void* d_out, int out_size, void* d_ws, size_t ws_size,
                              hipStream_t stream) {
  (void)in_sizes; (void)n_in; (void)out_size; (void)ws_size;
  const float* dx  = (const float*)d_in[0];
  const float* xin = (const float*)d_in[1];
  const float* h0  = (const float*)d_in[2];
  const float* W1  = (const float*)d_in[3];
  const float* b1  = (const float*)d_in[4];
  const float* W2  = (const float*)d_in[5];
  const float* b2  = (const float*)d_in[6];
  const float* W3  = (const float*)d_in[7];
  const float* b3  = (const float*)d_in[8];
  const float* W4  = (const float*)d_in[9];
  const float* b4  = (const float*)d_in[10];
  const float* Wih = (const float*)d_in[11];
  const float* Whh = (const float*)d_in[12];
  const float* bih = (const float*)d_in[13];
  const float* bhh = (const float*)d_in[14];
  const float* Wfc = (const float*)d_in[15];
  const float* bfc = (const float*)d_in[16];

  char* ws = (char*)d_ws;
  float*        bz  = (float*)(ws + OFF_BZ);
  float*        bc  = (float*)(ws + OFF_BC);
  unsigned int* WzP = (unsigned int*)(ws + OFF_WZP);
  unsigned int* WcP = (unsigned int*)(ws + OFF_WCP);
  _Float16*     w2h = (_Float16*)(ws + OFF_W2H);

  prep_all<<<273, 256, 0, stream>>>(dx, W1, Whh, b1, bhh, Wih, W4, b4, bih,
                                    W2, b2, WzP, bz, bc, WcP, w2h);
  decoder_main<<<64, 256, 0, stream>>>(dx, xin, h0, W3, b3, Wfc, bfc,
                                       WzP, bz, WcP, bc, w2h, (float*)d_out);
}